// Round 13
// baseline (109.378 us; speedup 1.0000x reference)
//
#include <hip/hip_runtime.h>

#define SEQ 1024
#define HEADS 16
#define HD 64
#define EMB 1024

typedef short bf16x8 __attribute__((ext_vector_type(8)));
typedef float f32x4 __attribute__((ext_vector_type(4)));

// pack two f32 -> u32 of 2 bf16 (lo = a, hi = b)
static __device__ __forceinline__ unsigned cvtpk(float a, float b) {
  unsigned r;
  asm("v_cvt_pk_bf16_f32 %0, %1, %2" : "=v"(r) : "v"(a), "v"(b));
  return r;
}

static __device__ __forceinline__ void gload_lds16(const void* g, void* l) {
  __builtin_amdgcn_global_load_lds((const __attribute__((address_space(1))) unsigned int*)g,
                                   (__attribute__((address_space(3))) unsigned int*)l,
                                   16, 0, 0);
}

// ---------------- fused prep + projections (unchanged from r10) ----------------
__global__ __launch_bounds__(256) void k_pp(const int* __restrict__ mask,
                                            const float* __restrict__ Wo,
                                            const float* __restrict__ Wv,
                                            const float* __restrict__ Wq,
                                            const float* __restrict__ Wk,
                                            const float* __restrict__ values,
                                            const float* __restrict__ query,
                                            const float* __restrict__ key,
                                            unsigned long long* __restrict__ mb,
                                            unsigned short* __restrict__ wob,
                                            unsigned short* __restrict__ vb,
                                            unsigned short* __restrict__ qb,
                                            unsigned short* __restrict__ kb) {
  __shared__ unsigned short Wl[64][64];
  const unsigned tid = threadIdx.x;
  const unsigned b = blockIdx.x;

  if (b < 3072) {
    const int lane = tid & 63, c = lane & 15, g = lane >> 4;
    const int wid = b * 4 + (tid >> 6);
    const int t = wid >> 12;
    const int rem = wid & 4095;
    const int n = rem >> 10, h = (rem >> 6) & 15, lb = rem & 63;

    const float* x; unsigned short* out;
    if (t == 0)      { x = values; out = vb; }
    else if (t == 1) { x = query;  out = qb; }
    else             { x = key;    out = kb; }
    const float* Wf = (t == 0) ? Wv : (t == 1) ? Wq : Wk;
    const float sc = (t == 1) ? 0.045084220027786356f : 1.0f;  // log2e/32 for Wq

    {
      const int row = tid >> 2, c0 = (tid & 3) * 16;
      const float4 f0 = *(const float4*)(Wf + row * 64 + c0);
      const float4 f1 = *(const float4*)(Wf + row * 64 + c0 + 4);
      const float4 f2 = *(const float4*)(Wf + row * 64 + c0 + 8);
      const float4 f3 = *(const float4*)(Wf + row * 64 + c0 + 12);
      uint4 u0, u1;
      u0.x = cvtpk(f0.x * sc, f0.y * sc); u0.y = cvtpk(f0.z * sc, f0.w * sc);
      u0.z = cvtpk(f1.x * sc, f1.y * sc); u0.w = cvtpk(f1.z * sc, f1.w * sc);
      u1.x = cvtpk(f2.x * sc, f2.y * sc); u1.y = cvtpk(f2.z * sc, f2.w * sc);
      u1.z = cvtpk(f3.x * sc, f3.y * sc); u1.w = cvtpk(f3.z * sc, f3.w * sc);
      const int s0 = ((c0 >> 3) ^ (row & 7)) << 4;
      const int s1 = (((c0 >> 3) + 1) ^ (row & 7)) << 4;
      *(uint4*)((char*)&Wl[0][0] + row * 128 + s0) = u0;
      *(uint4*)((char*)&Wl[0][0] + row * 128 + s1) = u1;
    }
    __syncthreads();

    bf16x8 bfr[4][2];
    #pragma unroll
    for (int cb = 0; cb < 4; ++cb) {
      const int row = cb * 16 + c;
      #pragma unroll
      for (int ks = 0; ks < 2; ++ks)
        bfr[cb][ks] = *(const bf16x8*)((char*)&Wl[0][0] + row * 128 +
                                       (((ks * 4 + g) ^ (c & 7)) << 4));
    }

    bf16x8 a[2];
    const float* xr = x + ((size_t)n * SEQ + lb * 16 + c) * EMB + h * HD;
    #pragma unroll
    for (int ks = 0; ks < 2; ++ks) {
      const float4 f0 = *(const float4*)(xr + ks * 32 + g * 8);
      const float4 f1 = *(const float4*)(xr + ks * 32 + g * 8 + 4);
      uint4 u;
      u.x = cvtpk(f0.x, f0.y); u.y = cvtpk(f0.z, f0.w);
      u.z = cvtpk(f1.x, f1.y); u.w = cvtpk(f1.z, f1.w);
      a[ks] = __builtin_bit_cast(bf16x8, u);
    }

    f32x4 acc[4] = {};
    #pragma unroll
    for (int cb = 0; cb < 4; ++cb)
      #pragma unroll
      for (int ks = 0; ks < 2; ++ks)
        acc[cb] = __builtin_amdgcn_mfma_f32_16x16x32_bf16(a[ks], bfr[cb][ks], acc[cb], 0, 0, 0);

    if (t == 0) {
      unsigned short* vt = out + (size_t)(n * HEADS + h) * (HD * SEQ);
      const int key0 = lb * 16 + 4 * g;
      #pragma unroll
      for (int cb = 0; cb < 4; ++cb) {
        const unsigned w0 = cvtpk(acc[cb][0], acc[cb][1]);
        const unsigned w1 = cvtpk(acc[cb][2], acc[cb][3]);
        *(uint2*)(vt + (size_t)(cb * 16 + c) * SEQ + key0) = make_uint2(w0, w1);
      }
    } else {
      unsigned short* op = out + ((size_t)(n * HEADS + h) * SEQ + lb * 16) * HD;
      #pragma unroll
      for (int r = 0; r < 4; ++r) {
        const unsigned w0 = cvtpk(acc[0][r], acc[1][r]);
        const unsigned w1 = cvtpk(acc[2][r], acc[3][r]);
        *(uint2*)(op + (4 * g + r) * HD + 4 * c) = make_uint2(w0, w1);
      }
    }
  } else if (b < 7168) {
    const unsigned lane = tid & 63u;
    const unsigned gwb = (b - 3072) * 16u + (tid >> 6) * 4u;
    #pragma unroll
    for (int it = 0; it < 4; ++it) {
      const unsigned gw = gwb + it;
      const int v = mask[(size_t)gw * 64u + lane];
      const unsigned long long bits = __ballot(v != 0);
      if (lane == 0) {
        const unsigned n = gw >> 14, qrow = (gw >> 4) & 1023u, ktile = gw & 15u;
        mb[((size_t)n * 16 + ktile) * 1024 + qrow] = bits;
      }
    }
  } else {
    const unsigned gid = (b - 7168) * 256u + tid;
    const unsigned e = gid >> 8, rem = gid & 255u;
    const unsigned blk = rem >> 4, cc = rem & 15u;
    const float* src = Wo + (size_t)e * 1024 + blk * 64 + cc;
    const unsigned w0 = cvtpk(src[0], src[16]);
    const unsigned w1 = cvtpk(src[32], src[48]);
    *(uint2*)(wob + (size_t)gid * 4) = make_uint2(w0, w1);
  }
}

// ---------------- flash attention: r10 structure at KVBLK=32, 8 blocks/CU ----------------
// block = (n, h, 64 q-rows); 4 waves x 16 q-rows, shared 32-key K/V tile (dbuf, 16KB LDS).
// Masks register-double-buffered (no LDS, loads ordered so compiler auto-waits never
// drain the staging prefetch). Counted vmcnt(3)/iter. Swapped QK^T, in-register P,
// max-free softmax, l via MFMA-ones. Grid 1024, bid%8 = nh%8 (XCD locality).
__global__ __launch_bounds__(256, 8) void k_attn(const unsigned short* __restrict__ qb,
                                                 const unsigned short* __restrict__ kb,
                                                 const unsigned short* __restrict__ vb,
                                                 const unsigned long long* __restrict__ mb,
                                                 unsigned short* __restrict__ ob) {
  const int tid = threadIdx.x;
  const int w = tid >> 6, lane = tid & 63;
  const int c = lane & 15, g = lane >> 4;
  const int bid = blockIdx.x;
  const int nh = bid & 63, q64 = bid >> 6;
  const int n = nh >> 4, h = nh & 15;
  const int qlo = q64 * 64 + w * 16;

  __shared__ unsigned short Ks[2][32][64];   // [buf][rho][dpos], col-swz ^(rho&7)
  __shared__ unsigned short Vs[2][64][32];   // [buf][d][keypos], slot-swz ^((d>>1)&3)

  char* const Kb0 = (char*)&Ks[0][0][0];
  char* const Vb0 = (char*)&Vs[0][0][0];

  const size_t nhb = (size_t)(n * HEADS + h) * (SEQ * HD);
  const unsigned short* qp = qb + nhb;
  const char* kpB = (const char*)(kb + nhb);
  const char* vpB = (const char*)(vb + nhb);   // V^T [64][1024], row pitch 2048B

  // Q B-frags first (oldest outstanding): qa[ks] = Q[qlo+c][dpos ks*32+8g+j]
  bf16x8 qa[2];
  #pragma unroll
  for (int ks = 0; ks < 2; ++ks)
    qa[ks] = *(const bf16x8*)(qp + (size_t)(qlo + c) * HD + ks * 32 + g * 8);

  // staging addresses: 1 K + 1 V gload_lds per thread per tile (4KB each)
  const char* kS; const char* vS; int sOf;
  {
    const int off = tid * 16;
    sOf = off;
    // K: LDS row rho (128B) holds key kappa(rho)=4*(rho>>4)+8*((rho>>2)&3)+(rho&3)
    const int rho = off >> 7, sl = (off >> 4) & 7;
    const int kap = 4 * (rho >> 4) + 8 * ((rho >> 2) & 3) + (rho & 3);
    kS = kpB + (size_t)kap * 128 + ((sl ^ (rho & 7)) << 4);
    // V: LDS row d (64B); source slot pre-swizzled ^((d>>1)&3)
    const int d = off >> 6, sl2 = (off >> 4) & 3;
    vS = vpB + (size_t)d * 2048 + ((sl2 ^ ((d >> 1) & 3)) << 4);
  }

  // mask: u64 per (n, kt64, qrow); this lane's row = qlo + c
  const char* const mgb = (const char*)mb + ((size_t)(n * 16) * 1024 + qlo + c) * 8;

  bf16x8 ones;
  #pragma unroll
  for (int j = 0; j < 8; ++j) ones[j] = (short)0x3F80;

  f32x4 o[4] = {};
  f32x4 lacc = {};
  unsigned mcur, mnxt;

#define STG(buf, t_) do {                                              \
    gload_lds16(kS + (size_t)(t_) * 4096, Kb0 + (buf) * 4096 + sOf);   \
    gload_lds16(vS + (t_) * 64, Vb0 + (buf) * 4096 + sOf);             \
  } while (0)

  // prologue: mask(0) then STG(0)  (mask older than stages)
  mnxt = *(const unsigned*)(mgb);
  STG(0, 0);

  for (int t = 0; t < 32; ++t) {
    const int cur = t & 1;
    mcur = mnxt;   // compiler auto-wait here retires ONLY the mask load (vmcnt(2))

    if (t < 31) {
      mnxt = *(const unsigned*)(mgb + (size_t)((t + 1) >> 1) * 8192 + ((t + 1) & 1) * 4);
      STG(cur ^ 1, t + 1);
      asm volatile("s_waitcnt vmcnt(3)" ::: "memory");  // tile t landed; t+1 (+mask) in flight
    } else {
      asm volatile("s_waitcnt vmcnt(0)" ::: "memory");
    }
    asm volatile("s_barrier" ::: "memory");

    char* const Kc = Kb0 + cur * 4096;
    char* const Vc = Vb0 + cur * 4096;

    // K A-frags: kf[sub][ks] lane(c,g) = K[kappa(sub*16+c)][dpos ks*32+8g+j]
    bf16x8 kf[2][2];
    #pragma unroll
    for (int sub = 0; sub < 2; ++sub) {
      const int rho = sub * 16 + c;   // rho&7 == c&7
      #pragma unroll
      for (int ks = 0; ks < 2; ++ks)
        kf[sub][ks] = *(const bf16x8*)(Kc + rho * 128 + (((ks * 4 + g) ^ (c & 7)) << 4));
    }

    // S^T = K * Q^T : s0[r]=S[key 8g+r][qrow c], s1[r]=S[key 8g+4+r][qrow c]
    f32x4 s0 = {}, s1 = {};
    __builtin_amdgcn_s_setprio(1);
    s0 = __builtin_amdgcn_mfma_f32_16x16x32_bf16(kf[0][0], qa[0], s0, 0, 0, 0);
    s0 = __builtin_amdgcn_mfma_f32_16x16x32_bf16(kf[0][1], qa[1], s0, 0, 0, 0);
    s1 = __builtin_amdgcn_mfma_f32_16x16x32_bf16(kf[1][0], qa[0], s1, 0, 0, 0);
    s1 = __builtin_amdgcn_mfma_f32_16x16x32_bf16(kf[1][1], qa[1], s1, 0, 0, 0);
    __builtin_amdgcn_s_setprio(0);

    // V B-frags (issued before exp2 so LDS latency hides under VALU)
    bf16x8 vf[4];
    #pragma unroll
    for (int db = 0; db < 4; ++db) {
      const int d = db * 16 + c;
      vf[db] = *(const bf16x8*)(Vc + d * 64 + ((g ^ ((c >> 1) & 3)) << 4));
    }

    // softmax numerators -> PV A-frag word order (elem j <-> key 8g+j)
    const unsigned x = mcur >> (8 * g);
    const float p0 = (x & 1u)   ? __builtin_exp2f(s0[0]) : 0.f;
    const float p1 = (x & 2u)   ? __builtin_exp2f(s0[1]) : 0.f;
    const float p2 = (x & 4u)   ? __builtin_exp2f(s0[2]) : 0.f;
    const float p3 = (x & 8u)   ? __builtin_exp2f(s0[3]) : 0.f;
    const float p4 = (x & 16u)  ? __builtin_exp2f(s1[0]) : 0.f;
    const float p5 = (x & 32u)  ? __builtin_exp2f(s1[1]) : 0.f;
    const float p6 = (x & 64u)  ? __builtin_exp2f(s1[2]) : 0.f;
    const float p7 = (x & 128u) ? __builtin_exp2f(s1[3]) : 0.f;
    const uint4 pu = make_uint4(cvtpk(p0, p1), cvtpk(p2, p3),
                                cvtpk(p4, p5), cvtpk(p6, p7));
    const bf16x8 pa = __builtin_bit_cast(bf16x8, pu);

    // O += P V ; l += P * ones   (single K=32 MFMA per d-block)
    __builtin_amdgcn_s_setprio(1);
    #pragma unroll
    for (int db = 0; db < 4; ++db)
      o[db] = __builtin_amdgcn_mfma_f32_16x16x32_bf16(pa, vf[db], o[db], 0, 0, 0);
    lacc = __builtin_amdgcn_mfma_f32_16x16x32_bf16(pa, ones, lacc, 0, 0, 0);
    __builtin_amdgcn_s_setprio(0);

    if (t < 31) asm volatile("s_barrier" ::: "memory");   // readers done before overwrite
  }
#undef STG

  // epilogue: lane(c,g) holds O[qrow=4g+r][e=db*16+c], l[qrow=4g+r]
  #pragma unroll
  for (int r = 0; r < 4; ++r) {
    const float inv = 1.0f / lacc[r];
    const unsigned w0 = cvtpk(o[0][r] * inv, o[1][r] * inv);
    const unsigned w1 = cvtpk(o[2][r] * inv, o[3][r] * inv);
    *(uint2*)(ob + ((size_t)n * SEQ + qlo + 4 * g + r) * EMB + h * 64 + 4 * c) =
        make_uint2(w0, w1);
  }
}

// ---------------- out-proj GEMM (unchanged from r10) ----------------
__global__ __launch_bounds__(256, 2) void k_gemm(const unsigned short* __restrict__ A,
                                                 const unsigned short* __restrict__ B,
                                                 const float* __restrict__ bo,
                                                 float* __restrict__ C) {
  const int tid = threadIdx.x;
  const int w = tid >> 6, lane = tid & 63;
  const int c = lane & 15, g = lane >> 4;
  const int bm = blockIdx.x & 31, bn = blockIdx.x >> 5;
  const int m0 = bm * 128, n0 = bn * 64;

  __shared__ unsigned short As[2][128][64];
  __shared__ unsigned short Bs[2][64][64];

  const char* aSrc[4]; int aOff[4];
  const char* bSrc[2]; int bOff[2];
  #pragma unroll
  for (int i = 0; i < 4; ++i) {
    const int off = i * 4096 + tid * 16;
    const int row = off >> 7, slot = (off >> 4) & 7;
    const int sw = (slot ^ (row & 7)) << 4;
    aSrc[i] = (const char*)A + (size_t)(m0 + row) * 2048 + sw;
    aOff[i] = off;
  }
  #pragma unroll
  for (int i = 0; i < 2; ++i) {
    const int off = i * 4096 + tid * 16;
    const int row = off >> 7, slot = (off >> 4) & 7;
    const int sw = (slot ^ (row & 7)) << 4;
    bSrc[i] = (const char*)B + (size_t)(n0 + row) * 2048 + sw;
    bOff[i] = off;
  }

  f32x4 acc[2][4] = {};

#define STAGE(buf, kt_) do {                                                  \
    _Pragma("unroll")                                                         \
    for (int i = 0; i < 4; ++i)                                               \
      gload_lds16(aSrc[i] + (kt_) * 128, (char*)&As[buf][0][0] + aOff[i]);    \
    _Pragma("unroll")                                                         \
    for (int i = 0; i < 2; ++i)                                               \
      gload_lds16(bSrc[i] + (kt_) * 128, (char*)&Bs[buf][0][0] + bOff[i]);    \
  } while (0)

  STAGE(0, 0);

  for (int kt = 0; kt < 16; ++kt) {
    const int cur = kt & 1;
    if (kt < 15) {
      STAGE(cur ^ 1, kt + 1);
      asm volatile("s_waitcnt vmcnt(6)" ::: "memory");
    } else {
      asm volatile("s_waitcnt vmcnt(0)" ::: "memory");
    }
    asm volatile("s_barrier" ::: "memory");

    #pragma unroll
    for (int ks = 0; ks < 2; ++ks) {
      bf16x8 af[2], bf_[4];
      #pragma unroll
      for (int i = 0; i < 2; ++i) {
        const int row = w * 32 + i * 16 + c;
        af[i] = *(const bf16x8*)((char*)&As[cur][0][0] + row * 128 +
                                 (((ks * 4 + g) ^ (c & 7)) << 4));
      }
      #pragma unroll
      for (int j = 0; j < 4; ++j) {
        const int row = j * 16 + c;
        bf_[j] = *(const bf16x8*)((char*)&Bs[cur][0][0] + row * 128 +
                                  (((ks * 4 + g) ^ (c & 7)) << 4));
      }
      __builtin_amdgcn_s_setprio(1);
      #pragma unroll
      for (int i = 0; i < 2; ++i)
        #pragma unroll
        for (int j = 0; j < 4; ++j)
          acc[i][j] = __builtin_amdgcn_mfma_f32_16x16x32_bf16(af[i], bf_[j], acc[i][j], 0, 0, 0);
      __builtin_amdgcn_s_setprio(0);
    }

    if (kt < 15) asm volatile("s_barrier" ::: "memory");
  }
#undef STAGE

  #pragma unroll
  for (int j = 0; j < 4; ++j) {
    const int col = n0 + j * 16 + c;
    const float bv = bo[col];
    #pragma unroll
    for (int i = 0; i < 2; ++i) {
      const int rowb = m0 + w * 32 + i * 16 + 4 * g;
      #pragma unroll
      for (int r = 0; r < 4; ++r)
        C[(size_t)(rowb + r) * 1024 + col] = acc[i][j][r] + bv;
    }
  }
}

extern "C" void kernel_launch(void* const* d_in, const int* in_sizes, int n_in,
                              void* d_out, int out_size, void* d_ws, size_t ws_size,
                              hipStream_t stream) {
  const float* values = (const float*)d_in[0];
  const float* query  = (const float*)d_in[1];
  const float* key    = (const float*)d_in[2];
  const int*   mask   = (const int*)d_in[3];
  const float* Wv     = (const float*)d_in[4];
  const float* Wk     = (const float*)d_in[5];
  const float* Wq     = (const float*)d_in[6];
  const float* Wo     = (const float*)d_in[7];
  const float* bo     = (const float*)d_in[8];
  float* out = (float*)d_out;

  char* ws = (char*)d_ws;
  unsigned short* qb = (unsigned short*)(ws);                            // 8MB  [N][H][S][Dpi]
  unsigned short* kb = (unsigned short*)(ws + (size_t)8 * 1024 * 1024);  // 8MB  [N][H][S][Dpi]
  unsigned short* vb = (unsigned short*)(ws + (size_t)16 * 1024 * 1024); // 8MB  V^T [N][H][D][S]
  unsigned short* ob = (unsigned short*)(ws + (size_t)24 * 1024 * 1024); // 8MB  [N][S][Epi]
  unsigned long long* mb = (unsigned long long*)(ws + (size_t)32 * 1024 * 1024);   // 512KB
  unsigned short* wob = (unsigned short*)(ws + (size_t)33 * 1024 * 1024);          // 2MB

  k_pp<<<8192, 256, 0, stream>>>(mask, Wo, Wv, Wq, Wk, values, query, key, mb, wob, vb, qb, kb);
  k_attn<<<1024, 256, 0, stream>>>(qb, kb, vb, mb, ob);
  k_gemm<<<512, 256, 0, stream>>>(ob, wob, bo, out);
}

// Round 14
// 76.109 us; speedup vs baseline: 1.4371x; 1.4371x over previous
//
#include <hip/hip_runtime.h>

#define SEQ 1024
#define HEADS 16
#define HD 64
#define EMB 1024

typedef short bf16x8 __attribute__((ext_vector_type(8)));
typedef float f32x4 __attribute__((ext_vector_type(4)));

// pack two f32 -> u32 of 2 bf16 (lo = a, hi = b)
static __device__ __forceinline__ unsigned cvtpk(float a, float b) {
  unsigned r;
  asm("v_cvt_pk_bf16_f32 %0, %1, %2" : "=v"(r) : "v"(a), "v"(b));
  return r;
}

static __device__ __forceinline__ void gload_lds16(const void* g, void* l) {
  __builtin_amdgcn_global_load_lds((const __attribute__((address_space(1))) unsigned int*)g,
                                   (__attribute__((address_space(3))) unsigned int*)l,
                                   16, 0, 0);
}

// ---------------- fused prep + projections (r10 verbatim) ----------------
__global__ __launch_bounds__(256) void k_pp(const int* __restrict__ mask,
                                            const float* __restrict__ Wo,
                                            const float* __restrict__ Wv,
                                            const float* __restrict__ Wq,
                                            const float* __restrict__ Wk,
                                            const float* __restrict__ values,
                                            const float* __restrict__ query,
                                            const float* __restrict__ key,
                                            unsigned long long* __restrict__ mb,
                                            unsigned short* __restrict__ wob,
                                            unsigned short* __restrict__ vb,
                                            unsigned short* __restrict__ qb,
                                            unsigned short* __restrict__ kb) {
  __shared__ unsigned short Wl[64][64];
  const unsigned tid = threadIdx.x;
  const unsigned b = blockIdx.x;

  if (b < 3072) {
    const int lane = tid & 63, c = lane & 15, g = lane >> 4;
    const int wid = b * 4 + (tid >> 6);
    const int t = wid >> 12;
    const int rem = wid & 4095;
    const int n = rem >> 10, h = (rem >> 6) & 15, lb = rem & 63;

    const float* x; unsigned short* out;
    if (t == 0)      { x = values; out = vb; }
    else if (t == 1) { x = query;  out = qb; }
    else             { x = key;    out = kb; }
    const float* Wf = (t == 0) ? Wv : (t == 1) ? Wq : Wk;
    const float sc = (t == 1) ? 0.045084220027786356f : 1.0f;  // log2e/32 for Wq

    {
      const int row = tid >> 2, c0 = (tid & 3) * 16;
      const float4 f0 = *(const float4*)(Wf + row * 64 + c0);
      const float4 f1 = *(const float4*)(Wf + row * 64 + c0 + 4);
      const float4 f2 = *(const float4*)(Wf + row * 64 + c0 + 8);
      const float4 f3 = *(const float4*)(Wf + row * 64 + c0 + 12);
      uint4 u0, u1;
      u0.x = cvtpk(f0.x * sc, f0.y * sc); u0.y = cvtpk(f0.z * sc, f0.w * sc);
      u0.z = cvtpk(f1.x * sc, f1.y * sc); u0.w = cvtpk(f1.z * sc, f1.w * sc);
      u1.x = cvtpk(f2.x * sc, f2.y * sc); u1.y = cvtpk(f2.z * sc, f2.w * sc);
      u1.z = cvtpk(f3.x * sc, f3.y * sc); u1.w = cvtpk(f3.z * sc, f3.w * sc);
      const int s0 = ((c0 >> 3) ^ (row & 7)) << 4;
      const int s1 = (((c0 >> 3) + 1) ^ (row & 7)) << 4;
      *(uint4*)((char*)&Wl[0][0] + row * 128 + s0) = u0;
      *(uint4*)((char*)&Wl[0][0] + row * 128 + s1) = u1;
    }
    __syncthreads();

    bf16x8 bfr[4][2];
    #pragma unroll
    for (int cb = 0; cb < 4; ++cb) {
      const int row = cb * 16 + c;
      #pragma unroll
      for (int ks = 0; ks < 2; ++ks)
        bfr[cb][ks] = *(const bf16x8*)((char*)&Wl[0][0] + row * 128 +
                                       (((ks * 4 + g) ^ (c & 7)) << 4));
    }

    bf16x8 a[2];
    const float* xr = x + ((size_t)n * SEQ + lb * 16 + c) * EMB + h * HD;
    #pragma unroll
    for (int ks = 0; ks < 2; ++ks) {
      const float4 f0 = *(const float4*)(xr + ks * 32 + g * 8);
      const float4 f1 = *(const float4*)(xr + ks * 32 + g * 8 + 4);
      uint4 u;
      u.x = cvtpk(f0.x, f0.y); u.y = cvtpk(f0.z, f0.w);
      u.z = cvtpk(f1.x, f1.y); u.w = cvtpk(f1.z, f1.w);
      a[ks] = __builtin_bit_cast(bf16x8, u);
    }

    f32x4 acc[4] = {};
    #pragma unroll
    for (int cb = 0; cb < 4; ++cb)
      #pragma unroll
      for (int ks = 0; ks < 2; ++ks)
        acc[cb] = __builtin_amdgcn_mfma_f32_16x16x32_bf16(a[ks], bfr[cb][ks], acc[cb], 0, 0, 0);

    if (t == 0) {
      unsigned short* vt = out + (size_t)(n * HEADS + h) * (HD * SEQ);
      const int key0 = lb * 16 + 4 * g;
      #pragma unroll
      for (int cb = 0; cb < 4; ++cb) {
        const unsigned w0 = cvtpk(acc[cb][0], acc[cb][1]);
        const unsigned w1 = cvtpk(acc[cb][2], acc[cb][3]);
        *(uint2*)(vt + (size_t)(cb * 16 + c) * SEQ + key0) = make_uint2(w0, w1);
      }
    } else {
      unsigned short* op = out + ((size_t)(n * HEADS + h) * SEQ + lb * 16) * HD;
      #pragma unroll
      for (int r = 0; r < 4; ++r) {
        const unsigned w0 = cvtpk(acc[0][r], acc[1][r]);
        const unsigned w1 = cvtpk(acc[2][r], acc[3][r]);
        *(uint2*)(op + (4 * g + r) * HD + 4 * c) = make_uint2(w0, w1);
      }
    }
  } else if (b < 7168) {
    const unsigned lane = tid & 63u;
    const unsigned gwb = (b - 3072) * 16u + (tid >> 6) * 4u;
    #pragma unroll
    for (int it = 0; it < 4; ++it) {
      const unsigned gw = gwb + it;
      const int v = mask[(size_t)gw * 64u + lane];
      const unsigned long long bits = __ballot(v != 0);
      if (lane == 0) {
        const unsigned n = gw >> 14, qrow = (gw >> 4) & 1023u, ktile = gw & 15u;
        mb[((size_t)n * 16 + ktile) * 1024 + qrow] = bits;
      }
    }
  } else {
    const unsigned gid = (b - 7168) * 256u + tid;
    const unsigned e = gid >> 8, rem = gid & 255u;
    const unsigned blk = rem >> 4, cc = rem & 15u;
    const float* src = Wo + (size_t)e * 1024 + blk * 64 + cc;
    const unsigned w0 = cvtpk(src[0], src[16]);
    const unsigned w1 = cvtpk(src[32], src[48]);
    *(uint2*)(wob + (size_t)gid * 4) = make_uint2(w0, w1);
  }
}

// ---------------- flash attention: r10 structure + circular tile-phase stagger ----------
// block = (n, h, 64 q-rows); 4 waves x 16 q-rows. Grid 1024 (4/CU), bid%8 = nh%8 (XCD).
// Tiles visited in circular order starting at phase=(bid>>3)&15 (max-free softmax is
// order-independent) to de-phase-lock co-resident blocks' pipe usage.
// Mask bits staged to LDS in prologue; counted vmcnt(4). LDS 40960B = 4 blocks/CU.
__global__ __launch_bounds__(256, 4) void k_attn(const unsigned short* __restrict__ qb,
                                                 const unsigned short* __restrict__ kb,
                                                 const unsigned short* __restrict__ vb,
                                                 const unsigned long long* __restrict__ mb,
                                                 unsigned short* __restrict__ ob) {
  const int tid = threadIdx.x;
  const int w = tid >> 6, lane = tid & 63;
  const int c = lane & 15, g = lane >> 4;
  const int bid = blockIdx.x;
  const int nh = bid & 63, q64 = bid >> 6;
  const int n = nh >> 4, h = nh & 15;
  const int qlo = q64 * 64 + w * 16;
  const int phase = (bid >> 3) & 15;

  __shared__ unsigned short Ks[2][64][64];   // [buf][A-row rho][64], col-swz ^(rho&7)
  __shared__ unsigned short Vs[2][64][64];   // [buf][d][keypos], col-swz ^(d&7)
  __shared__ unsigned long long Ml[16][64];  // mask bits [kt][local qrow]

  char* const Kb0 = (char*)&Ks[0][0][0];
  char* const Vb0 = (char*)&Vs[0][0][0];
  char* const Mb0 = (char*)&Ml[0][0];

  const size_t nhb = (size_t)(n * HEADS + h) * (SEQ * HD);
  const unsigned short* qp = qb + nhb;
  const char* kpB = (const char*)(kb + nhb);
  const char* vpB = (const char*)(vb + nhb);   // V^T [64][1024], row pitch 2048B

  // hoisted staging addresses: 2 K + 2 V loads per thread per tile
  const char* kSrc[2]; const char* vSrc[2]; int ldsOff[2];
  #pragma unroll
  for (int i = 0; i < 2; ++i) {
    const int off = i * 4096 + tid * 16;
    const int row = off >> 7, slot = (off >> 4) & 7;
    const int krow = ((row >> 4) & 1) * 32 + ((row >> 5) & 1) * 4 +
                     ((row >> 2) & 3) * 8 + (row & 3);   // kappa
    const int sw = (slot ^ (row & 7)) << 4;
    kSrc[i] = kpB + krow * 128 + sw;
    vSrc[i] = vpB + (size_t)row * 2048 + sw;
    ldsOff[i] = off;
  }

  // Q B-frags: lane(c,g) = Q[qrow=qlo+c][dpos=ks*32+8g+j]
  bf16x8 qa[2];
  #pragma unroll
  for (int ks = 0; ks < 2; ++ks)
    qa[ks] = *(const bf16x8*)(qp + (size_t)(qlo + c) * HD + ks * 32 + g * 8);

  bf16x8 ones;
  #pragma unroll
  for (int j = 0; j < 8; ++j) ones[j] = (short)0x3F80;

  f32x4 o[4] = {};
  f32x4 lacc = {};

#define STAGEKV(dstK, dstV, kt_) do {                                   \
    _Pragma("unroll")                                                   \
    for (int i = 0; i < 2; ++i) {                                       \
      gload_lds16(kSrc[i] + (size_t)(kt_) * 8192, (dstK) + ldsOff[i]);  \
      gload_lds16(vSrc[i] + (kt_) * 128, (dstV) + ldsOff[i]);           \
    }                                                                   \
  } while (0)

  // prologue: stage mask bits (8KB: 16 kt x 64 rows x 8B) then tile 'phase'
  #pragma unroll
  for (int i = 0; i < 2; ++i) {
    const int moff = i * 4096 + tid * 16;
    const int mkt = moff >> 9;                 // 512B per kt
    const char* msrc = (const char*)mb +
        ((size_t)(n * 16 + mkt) * 1024 + q64 * 64) * 8 + (moff & 511);
    gload_lds16(msrc, Mb0 + moff);
  }
  STAGEKV(Kb0, Vb0, phase);

  for (int t = 0; t < 16; ++t) {
    const int cur = t & 1;
    const int kt = (t + phase) & 15;
    char* const Kc = Kb0 + cur * 8192;
    char* const Vc = Vb0 + cur * 8192;
    if (t < 15) {
      const int ktn = (kt + 1) & 15;
      STAGEKV(Kb0 + (cur ^ 1) * 8192, Vb0 + (cur ^ 1) * 8192, ktn);
      asm volatile("s_waitcnt vmcnt(4)" ::: "memory");  // tile t (+mask) done, t+1 in flight
    } else {
      asm volatile("s_waitcnt vmcnt(0)" ::: "memory");
    }
    asm volatile("s_barrier" ::: "memory");

    // mask bits from LDS (no vmem in loop)
    const unsigned long long bits = Ml[kt][w * 16 + c];
    const unsigned blo = (unsigned)bits, bhi = (unsigned)(bits >> 32);

    // K A-frags: kf[sub][ks] lane(c,g) = A[row=c] of subtile sub = K[kappa(sub,c)]
    bf16x8 kf[4][2];
    #pragma unroll
    for (int sub = 0; sub < 4; ++sub) {
      const int rho = sub * 16 + c;     // rho&7 == c&7
      #pragma unroll
      for (int ks = 0; ks < 2; ++ks)
        kf[sub][ks] = *(const bf16x8*)(Kc + rho * 128 + (((ks * 4 + g) ^ (c & 7)) << 4));
    }

    // S^T = K * Q^T : s[sub] lane(c,g) = S[key=kappa(sub,4g+r)][qrow=c]
    f32x4 s[4];
    __builtin_amdgcn_s_setprio(1);
    #pragma unroll
    for (int sub = 0; sub < 4; ++sub) {
      f32x4 acc = {};
      acc = __builtin_amdgcn_mfma_f32_16x16x32_bf16(kf[sub][0], qa[0], acc, 0, 0, 0);
      acc = __builtin_amdgcn_mfma_f32_16x16x32_bf16(kf[sub][1], qa[1], acc, 0, 0, 0);
      s[sub] = acc;
    }
    __builtin_amdgcn_s_setprio(0);

    // V^T B-frags issued before the exp2 block (LDS latency hides under VALU)
    bf16x8 vf[4][2];
    #pragma unroll
    for (int db = 0; db < 4; ++db) {
      const int row = db * 16 + c;
      #pragma unroll
      for (int ks = 0; ks < 2; ++ks)
        vf[db][ks] = *(const bf16x8*)(Vc + row * 128 + (((ks * 4 + g) ^ (c & 7)) << 4));
    }

    // softmax numerators, in-register, directly into PV A-frag word order
    unsigned pw[2][4];
    #pragma unroll
    for (int sub = 0; sub < 4; ++sub) {
      const unsigned x = ((sub & 1) ? bhi : blo) >> (8 * g + ((sub >> 1) << 2));
      const float p0 = (x & 1u) ? __builtin_exp2f(s[sub][0]) : 0.f;
      const float p1 = (x & 2u) ? __builtin_exp2f(s[sub][1]) : 0.f;
      const float p2 = (x & 4u) ? __builtin_exp2f(s[sub][2]) : 0.f;
      const float p3 = (x & 8u) ? __builtin_exp2f(s[sub][3]) : 0.f;
      pw[sub & 1][(sub >> 1) * 2 + 0] = cvtpk(p0, p1);
      pw[sub & 1][(sub >> 1) * 2 + 1] = cvtpk(p2, p3);
    }
    bf16x8 pa[2];
    pa[0] = __builtin_bit_cast(bf16x8, *(uint4*)&pw[0][0]);
    pa[1] = __builtin_bit_cast(bf16x8, *(uint4*)&pw[1][0]);

    // O += P V ; l += P * ones
    __builtin_amdgcn_s_setprio(1);
    #pragma unroll
    for (int ks = 0; ks < 2; ++ks) {
      #pragma unroll
      for (int db = 0; db < 4; ++db)
        o[db] = __builtin_amdgcn_mfma_f32_16x16x32_bf16(pa[ks], vf[db][ks], o[db], 0, 0, 0);
      lacc = __builtin_amdgcn_mfma_f32_16x16x32_bf16(pa[ks], ones, lacc, 0, 0, 0);
    }
    __builtin_amdgcn_s_setprio(0);

    if (t < 15) asm volatile("s_barrier" ::: "memory");   // readers done before overwrite
  }
#undef STAGEKV

  // epilogue: lane(c,g) holds O[qrow=4g+r][e=db*16+c], l[qrow=4g+r]
  #pragma unroll
  for (int r = 0; r < 4; ++r) {
    const float inv = 1.0f / lacc[r];
    const unsigned w0 = cvtpk(o[0][r] * inv, o[1][r] * inv);
    const unsigned w1 = cvtpk(o[2][r] * inv, o[3][r] * inv);
    *(uint2*)(ob + ((size_t)n * SEQ + qlo + 4 * g + r) * EMB + h * 64 + 4 * c) =
        make_uint2(w0, w1);
  }
}

// ---------------- out-proj GEMM (r10 verbatim) ----------------
__global__ __launch_bounds__(256, 2) void k_gemm(const unsigned short* __restrict__ A,
                                                 const unsigned short* __restrict__ B,
                                                 const float* __restrict__ bo,
                                                 float* __restrict__ C) {
  const int tid = threadIdx.x;
  const int w = tid >> 6, lane = tid & 63;
  const int c = lane & 15, g = lane >> 4;
  const int bm = blockIdx.x & 31, bn = blockIdx.x >> 5;
  const int m0 = bm * 128, n0 = bn * 64;

  __shared__ unsigned short As[2][128][64];
  __shared__ unsigned short Bs[2][64][64];

  const char* aSrc[4]; int aOff[4];
  const char* bSrc[2]; int bOff[2];
  #pragma unroll
  for (int i = 0; i < 4; ++i) {
    const int off = i * 4096 + tid * 16;
    const int row = off >> 7, slot = (off >> 4) & 7;
    const int sw = (slot ^ (row & 7)) << 4;
    aSrc[i] = (const char*)A + (size_t)(m0 + row) * 2048 + sw;
    aOff[i] = off;
  }
  #pragma unroll
  for (int i = 0; i < 2; ++i) {
    const int off = i * 4096 + tid * 16;
    const int row = off >> 7, slot = (off >> 4) & 7;
    const int sw = (slot ^ (row & 7)) << 4;
    bSrc[i] = (const char*)B + (size_t)(n0 + row) * 2048 + sw;
    bOff[i] = off;
  }

  f32x4 acc[2][4] = {};

#define STAGE(buf, kt_) do {                                                  \
    _Pragma("unroll")                                                         \
    for (int i = 0; i < 4; ++i)                                               \
      gload_lds16(aSrc[i] + (kt_) * 128, (char*)&As[buf][0][0] + aOff[i]);    \
    _Pragma("unroll")                                                         \
    for (int i = 0; i < 2; ++i)                                               \
      gload_lds16(bSrc[i] + (kt_) * 128, (char*)&Bs[buf][0][0] + bOff[i]);    \
  } while (0)

  STAGE(0, 0);

  for (int kt = 0; kt < 16; ++kt) {
    const int cur = kt & 1;
    if (kt < 15) {
      STAGE(cur ^ 1, kt + 1);
      asm volatile("s_waitcnt vmcnt(6)" ::: "memory");
    } else {
      asm volatile("s_waitcnt vmcnt(0)" ::: "memory");
    }
    asm volatile("s_barrier" ::: "memory");

    #pragma unroll
    for (int ks = 0; ks < 2; ++ks) {
      bf16x8 af[2], bf_[4];
      #pragma unroll
      for (int i = 0; i < 2; ++i) {
        const int row = w * 32 + i * 16 + c;
        af[i] = *(const bf16x8*)((char*)&As[cur][0][0] + row * 128 +
                                 (((ks * 4 + g) ^ (c & 7)) << 4));
      }
      #pragma unroll
      for (int j = 0; j < 4; ++j) {
        const int row = j * 16 + c;
        bf_[j] = *(const bf16x8*)((char*)&Bs[cur][0][0] + row * 128 +
                                  (((ks * 4 + g) ^ (c & 7)) << 4));
      }
      __builtin_amdgcn_s_setprio(1);
      #pragma unroll
      for (int i = 0; i < 2; ++i)
        #pragma unroll
        for (int j = 0; j < 4; ++j)
          acc[i][j] = __builtin_amdgcn_mfma_f32_16x16x32_bf16(af[i], bf_[j], acc[i][j], 0, 0, 0);
      __builtin_amdgcn_s_setprio(0);
    }

    if (kt < 15) asm volatile("s_barrier" ::: "memory");
  }
#undef STAGE

  #pragma unroll
  for (int j = 0; j < 4; ++j) {
    const int col = n0 + j * 16 + c;
    const float bv = bo[col];
    #pragma unroll
    for (int i = 0; i < 2; ++i) {
      const int rowb = m0 + w * 32 + i * 16 + 4 * g;
      #pragma unroll
      for (int r = 0; r < 4; ++r)
        C[(size_t)(rowb + r) * 1024 + col] = acc[i][j][r] + bv;
    }
  }
}

extern "C" void kernel_launch(void* const* d_in, const int* in_sizes, int n_in,
                              void* d_out, int out_size, void* d_ws, size_t ws_size,
                              hipStream_t stream) {
  const float* values = (const float*)d_in[0];
  const float* query  = (const float*)d_in[1];
  const float* key    = (const float*)d_in[2];
  const int*   mask   = (const int*)d_in[3];
  const float* Wv     = (const float*)d_in[4];
  const float* Wk     = (const float*)d_in[5];
  const float* Wq     = (const float*)d_in[6];
  const float* Wo     = (const float*)d_in[7];
  const float* bo     = (const float*)d_in[8];
  float* out = (float*)d_out;

  char* ws = (char*)d_ws;
  unsigned short* qb = (unsigned short*)(ws);                            // 8MB  [N][H][S][Dpi]
  unsigned short* kb = (unsigned short*)(ws + (size_t)8 * 1024 * 1024);  // 8MB  [N][H][S][Dpi]
  unsigned short* vb = (unsigned short*)(ws + (size_t)16 * 1024 * 1024); // 8MB  V^T [N][H][D][S]
  unsigned short* ob = (unsigned short*)(ws + (size_t)24 * 1024 * 1024); // 8MB  [N][S][Epi]
  unsigned long long* mb = (unsigned long long*)(ws + (size_t)32 * 1024 * 1024);   // 512KB
  unsigned short* wob = (unsigned short*)(ws + (size_t)33 * 1024 * 1024);          // 2MB

  k_pp<<<8192, 256, 0, stream>>>(mask, Wo, Wv, Wq, Wk, values, query, key, mb, wob, vb, qb, kb);
  k_attn<<<1024, 256, 0, stream>>>(qb, kb, vb, mb, ob);
  k_gemm<<<512, 256, 0, stream>>>(ob, wob, bo, out);
}

// Round 15
// 76.073 us; speedup vs baseline: 1.4378x; 1.0005x over previous
//
#include <hip/hip_runtime.h>

#define SEQ 1024
#define HEADS 16
#define HD 64
#define EMB 1024

typedef short bf16x8 __attribute__((ext_vector_type(8)));
typedef float f32x4 __attribute__((ext_vector_type(4)));

// pack two f32 -> u32 of 2 bf16 (lo = a, hi = b)
static __device__ __forceinline__ unsigned cvtpk(float a, float b) {
  unsigned r;
  asm("v_cvt_pk_bf16_f32 %0, %1, %2" : "=v"(r) : "v"(a), "v"(b));
  return r;
}

static __device__ __forceinline__ void gload_lds16(const void* g, void* l) {
  __builtin_amdgcn_global_load_lds((const __attribute__((address_space(1))) unsigned int*)g,
                                   (__attribute__((address_space(3))) unsigned int*)l,
                                   16, 0, 0);
}

// ---------------- fused prep + projections (r14 verbatim) ----------------
__global__ __launch_bounds__(256) void k_pp(const int* __restrict__ mask,
                                            const float* __restrict__ Wo,
                                            const float* __restrict__ Wv,
                                            const float* __restrict__ Wq,
                                            const float* __restrict__ Wk,
                                            const float* __restrict__ values,
                                            const float* __restrict__ query,
                                            const float* __restrict__ key,
                                            unsigned long long* __restrict__ mb,
                                            unsigned short* __restrict__ wob,
                                            unsigned short* __restrict__ vb,
                                            unsigned short* __restrict__ qb,
                                            unsigned short* __restrict__ kb) {
  __shared__ unsigned short Wl[64][64];
  const unsigned tid = threadIdx.x;
  const unsigned b = blockIdx.x;

  if (b < 3072) {
    const int lane = tid & 63, c = lane & 15, g = lane >> 4;
    const int wid = b * 4 + (tid >> 6);
    const int t = wid >> 12;
    const int rem = wid & 4095;
    const int n = rem >> 10, h = (rem >> 6) & 15, lb = rem & 63;

    const float* x; unsigned short* out;
    if (t == 0)      { x = values; out = vb; }
    else if (t == 1) { x = query;  out = qb; }
    else             { x = key;    out = kb; }
    const float* Wf = (t == 0) ? Wv : (t == 1) ? Wq : Wk;
    const float sc = (t == 1) ? 0.045084220027786356f : 1.0f;  // log2e/32 for Wq

    {
      const int row = tid >> 2, c0 = (tid & 3) * 16;
      const float4 f0 = *(const float4*)(Wf + row * 64 + c0);
      const float4 f1 = *(const float4*)(Wf + row * 64 + c0 + 4);
      const float4 f2 = *(const float4*)(Wf + row * 64 + c0 + 8);
      const float4 f3 = *(const float4*)(Wf + row * 64 + c0 + 12);
      uint4 u0, u1;
      u0.x = cvtpk(f0.x * sc, f0.y * sc); u0.y = cvtpk(f0.z * sc, f0.w * sc);
      u0.z = cvtpk(f1.x * sc, f1.y * sc); u0.w = cvtpk(f1.z * sc, f1.w * sc);
      u1.x = cvtpk(f2.x * sc, f2.y * sc); u1.y = cvtpk(f2.z * sc, f2.w * sc);
      u1.z = cvtpk(f3.x * sc, f3.y * sc); u1.w = cvtpk(f3.z * sc, f3.w * sc);
      const int s0 = ((c0 >> 3) ^ (row & 7)) << 4;
      const int s1 = (((c0 >> 3) + 1) ^ (row & 7)) << 4;
      *(uint4*)((char*)&Wl[0][0] + row * 128 + s0) = u0;
      *(uint4*)((char*)&Wl[0][0] + row * 128 + s1) = u1;
    }
    __syncthreads();

    bf16x8 bfr[4][2];
    #pragma unroll
    for (int cb = 0; cb < 4; ++cb) {
      const int row = cb * 16 + c;
      #pragma unroll
      for (int ks = 0; ks < 2; ++ks)
        bfr[cb][ks] = *(const bf16x8*)((char*)&Wl[0][0] + row * 128 +
                                       (((ks * 4 + g) ^ (c & 7)) << 4));
    }

    bf16x8 a[2];
    const float* xr = x + ((size_t)n * SEQ + lb * 16 + c) * EMB + h * HD;
    #pragma unroll
    for (int ks = 0; ks < 2; ++ks) {
      const float4 f0 = *(const float4*)(xr + ks * 32 + g * 8);
      const float4 f1 = *(const float4*)(xr + ks * 32 + g * 8 + 4);
      uint4 u;
      u.x = cvtpk(f0.x, f0.y); u.y = cvtpk(f0.z, f0.w);
      u.z = cvtpk(f1.x, f1.y); u.w = cvtpk(f1.z, f1.w);
      a[ks] = __builtin_bit_cast(bf16x8, u);
    }

    f32x4 acc[4] = {};
    #pragma unroll
    for (int cb = 0; cb < 4; ++cb)
      #pragma unroll
      for (int ks = 0; ks < 2; ++ks)
        acc[cb] = __builtin_amdgcn_mfma_f32_16x16x32_bf16(a[ks], bfr[cb][ks], acc[cb], 0, 0, 0);

    if (t == 0) {
      unsigned short* vt = out + (size_t)(n * HEADS + h) * (HD * SEQ);
      const int key0 = lb * 16 + 4 * g;
      #pragma unroll
      for (int cb = 0; cb < 4; ++cb) {
        const unsigned w0 = cvtpk(acc[cb][0], acc[cb][1]);
        const unsigned w1 = cvtpk(acc[cb][2], acc[cb][3]);
        *(uint2*)(vt + (size_t)(cb * 16 + c) * SEQ + key0) = make_uint2(w0, w1);
      }
    } else {
      unsigned short* op = out + ((size_t)(n * HEADS + h) * SEQ + lb * 16) * HD;
      #pragma unroll
      for (int r = 0; r < 4; ++r) {
        const unsigned w0 = cvtpk(acc[0][r], acc[1][r]);
        const unsigned w1 = cvtpk(acc[2][r], acc[3][r]);
        *(uint2*)(op + (4 * g + r) * HD + 4 * c) = make_uint2(w0, w1);
      }
    }
  } else if (b < 7168) {
    const unsigned lane = tid & 63u;
    const unsigned gwb = (b - 3072) * 16u + (tid >> 6) * 4u;
    #pragma unroll
    for (int it = 0; it < 4; ++it) {
      const unsigned gw = gwb + it;
      const int v = mask[(size_t)gw * 64u + lane];
      const unsigned long long bits = __ballot(v != 0);
      if (lane == 0) {
        const unsigned n = gw >> 14, qrow = (gw >> 4) & 1023u, ktile = gw & 15u;
        mb[((size_t)n * 16 + ktile) * 1024 + qrow] = bits;
      }
    }
  } else {
    const unsigned gid = (b - 7168) * 256u + tid;
    const unsigned e = gid >> 8, rem = gid & 255u;
    const unsigned blk = rem >> 4, cc = rem & 15u;
    const float* src = Wo + (size_t)e * 1024 + blk * 64 + cc;
    const unsigned w0 = cvtpk(src[0], src[16]);
    const unsigned w1 = cvtpk(src[32], src[48]);
    *(uint2*)(wob + (size_t)gid * 4) = make_uint2(w0, w1);
  }
}

// ---------------- flash attention (r14 verbatim — measured floor 40.7 us) ----------
__global__ __launch_bounds__(256, 4) void k_attn(const unsigned short* __restrict__ qb,
                                                 const unsigned short* __restrict__ kb,
                                                 const unsigned short* __restrict__ vb,
                                                 const unsigned long long* __restrict__ mb,
                                                 unsigned short* __restrict__ ob) {
  const int tid = threadIdx.x;
  const int w = tid >> 6, lane = tid & 63;
  const int c = lane & 15, g = lane >> 4;
  const int bid = blockIdx.x;
  const int nh = bid & 63, q64 = bid >> 6;
  const int n = nh >> 4, h = nh & 15;
  const int qlo = q64 * 64 + w * 16;
  const int phase = (bid >> 3) & 15;

  __shared__ unsigned short Ks[2][64][64];   // [buf][A-row rho][64], col-swz ^(rho&7)
  __shared__ unsigned short Vs[2][64][64];   // [buf][d][keypos], col-swz ^(d&7)
  __shared__ unsigned long long Ml[16][64];  // mask bits [kt][local qrow]

  char* const Kb0 = (char*)&Ks[0][0][0];
  char* const Vb0 = (char*)&Vs[0][0][0];
  char* const Mb0 = (char*)&Ml[0][0];

  const size_t nhb = (size_t)(n * HEADS + h) * (SEQ * HD);
  const unsigned short* qp = qb + nhb;
  const char* kpB = (const char*)(kb + nhb);
  const char* vpB = (const char*)(vb + nhb);   // V^T [64][1024], row pitch 2048B

  const char* kSrc[2]; const char* vSrc[2]; int ldsOff[2];
  #pragma unroll
  for (int i = 0; i < 2; ++i) {
    const int off = i * 4096 + tid * 16;
    const int row = off >> 7, slot = (off >> 4) & 7;
    const int krow = ((row >> 4) & 1) * 32 + ((row >> 5) & 1) * 4 +
                     ((row >> 2) & 3) * 8 + (row & 3);   // kappa
    const int sw = (slot ^ (row & 7)) << 4;
    kSrc[i] = kpB + krow * 128 + sw;
    vSrc[i] = vpB + (size_t)row * 2048 + sw;
    ldsOff[i] = off;
  }

  bf16x8 qa[2];
  #pragma unroll
  for (int ks = 0; ks < 2; ++ks)
    qa[ks] = *(const bf16x8*)(qp + (size_t)(qlo + c) * HD + ks * 32 + g * 8);

  bf16x8 ones;
  #pragma unroll
  for (int j = 0; j < 8; ++j) ones[j] = (short)0x3F80;

  f32x4 o[4] = {};
  f32x4 lacc = {};

#define STAGEKV(dstK, dstV, kt_) do {                                   \
    _Pragma("unroll")                                                   \
    for (int i = 0; i < 2; ++i) {                                       \
      gload_lds16(kSrc[i] + (size_t)(kt_) * 8192, (dstK) + ldsOff[i]);  \
      gload_lds16(vSrc[i] + (kt_) * 128, (dstV) + ldsOff[i]);           \
    }                                                                   \
  } while (0)

  #pragma unroll
  for (int i = 0; i < 2; ++i) {
    const int moff = i * 4096 + tid * 16;
    const int mkt = moff >> 9;                 // 512B per kt
    const char* msrc = (const char*)mb +
        ((size_t)(n * 16 + mkt) * 1024 + q64 * 64) * 8 + (moff & 511);
    gload_lds16(msrc, Mb0 + moff);
  }
  STAGEKV(Kb0, Vb0, phase);

  for (int t = 0; t < 16; ++t) {
    const int cur = t & 1;
    const int kt = (t + phase) & 15;
    char* const Kc = Kb0 + cur * 8192;
    char* const Vc = Vb0 + cur * 8192;
    if (t < 15) {
      const int ktn = (kt + 1) & 15;
      STAGEKV(Kb0 + (cur ^ 1) * 8192, Vb0 + (cur ^ 1) * 8192, ktn);
      asm volatile("s_waitcnt vmcnt(4)" ::: "memory");
    } else {
      asm volatile("s_waitcnt vmcnt(0)" ::: "memory");
    }
    asm volatile("s_barrier" ::: "memory");

    const unsigned long long bits = Ml[kt][w * 16 + c];
    const unsigned blo = (unsigned)bits, bhi = (unsigned)(bits >> 32);

    bf16x8 kf[4][2];
    #pragma unroll
    for (int sub = 0; sub < 4; ++sub) {
      const int rho = sub * 16 + c;     // rho&7 == c&7
      #pragma unroll
      for (int ks = 0; ks < 2; ++ks)
        kf[sub][ks] = *(const bf16x8*)(Kc + rho * 128 + (((ks * 4 + g) ^ (c & 7)) << 4));
    }

    f32x4 s[4];
    __builtin_amdgcn_s_setprio(1);
    #pragma unroll
    for (int sub = 0; sub < 4; ++sub) {
      f32x4 acc = {};
      acc = __builtin_amdgcn_mfma_f32_16x16x32_bf16(kf[sub][0], qa[0], acc, 0, 0, 0);
      acc = __builtin_amdgcn_mfma_f32_16x16x32_bf16(kf[sub][1], qa[1], acc, 0, 0, 0);
      s[sub] = acc;
    }
    __builtin_amdgcn_s_setprio(0);

    bf16x8 vf[4][2];
    #pragma unroll
    for (int db = 0; db < 4; ++db) {
      const int row = db * 16 + c;
      #pragma unroll
      for (int ks = 0; ks < 2; ++ks)
        vf[db][ks] = *(const bf16x8*)(Vc + row * 128 + (((ks * 4 + g) ^ (c & 7)) << 4));
    }

    unsigned pw[2][4];
    #pragma unroll
    for (int sub = 0; sub < 4; ++sub) {
      const unsigned x = ((sub & 1) ? bhi : blo) >> (8 * g + ((sub >> 1) << 2));
      const float p0 = (x & 1u) ? __builtin_exp2f(s[sub][0]) : 0.f;
      const float p1 = (x & 2u) ? __builtin_exp2f(s[sub][1]) : 0.f;
      const float p2 = (x & 4u) ? __builtin_exp2f(s[sub][2]) : 0.f;
      const float p3 = (x & 8u) ? __builtin_exp2f(s[sub][3]) : 0.f;
      pw[sub & 1][(sub >> 1) * 2 + 0] = cvtpk(p0, p1);
      pw[sub & 1][(sub >> 1) * 2 + 1] = cvtpk(p2, p3);
    }
    bf16x8 pa[2];
    pa[0] = __builtin_bit_cast(bf16x8, *(uint4*)&pw[0][0]);
    pa[1] = __builtin_bit_cast(bf16x8, *(uint4*)&pw[1][0]);

    __builtin_amdgcn_s_setprio(1);
    #pragma unroll
    for (int ks = 0; ks < 2; ++ks) {
      #pragma unroll
      for (int db = 0; db < 4; ++db)
        o[db] = __builtin_amdgcn_mfma_f32_16x16x32_bf16(pa[ks], vf[db][ks], o[db], 0, 0, 0);
      lacc = __builtin_amdgcn_mfma_f32_16x16x32_bf16(pa[ks], ones, lacc, 0, 0, 0);
    }
    __builtin_amdgcn_s_setprio(0);

    if (t < 15) asm volatile("s_barrier" ::: "memory");
  }
#undef STAGEKV

  #pragma unroll
  for (int r = 0; r < 4; ++r) {
    const float inv = 1.0f / lacc[r];
    const unsigned w0 = cvtpk(o[0][r] * inv, o[1][r] * inv);
    const unsigned w1 = cvtpk(o[2][r] * inv, o[3][r] * inv);
    *(uint2*)(ob + ((size_t)n * SEQ + qlo + 4 * g + r) * EMB + h * 64 + 4 * c) =
        make_uint2(w0, w1);
  }
}

// ---------------- out-proj GEMM: A/B experiment — 64x64 tile, grid 1024 (4 blocks/CU,
// 16 waves/CU), swizzled dbuf LDS, counted-vmcnt pipeline (r7 geometry isolated) --------
__global__ __launch_bounds__(256, 4) void k_gemm(const unsigned short* __restrict__ A,
                                                 const unsigned short* __restrict__ B,
                                                 const float* __restrict__ bo,
                                                 float* __restrict__ C) {
  const int tid = threadIdx.x;
  const int w = tid >> 6, lane = tid & 63;
  const int c = lane & 15, g = lane >> 4;
  const int bm = blockIdx.x & 63, bn = blockIdx.x >> 6;
  const int m0 = bm * 64, n0 = bn * 64;
  const int wr = w >> 1, wc = w & 1;

  __shared__ unsigned short As[2][64][64];
  __shared__ unsigned short Bs[2][64][64];

  // hoisted staging addresses: 2 A + 2 B loads per thread per K-step
  const char* aSrc[2]; const char* bSrc[2]; int ldsOff[2];
  #pragma unroll
  for (int i = 0; i < 2; ++i) {
    const int off = i * 4096 + tid * 16;
    const int row = off >> 7, slot = (off >> 4) & 7;
    const int sw = (slot ^ (row & 7)) << 4;
    aSrc[i] = (const char*)A + (size_t)(m0 + row) * 2048 + sw;
    bSrc[i] = (const char*)B + (size_t)(n0 + row) * 2048 + sw;
    ldsOff[i] = off;
  }

  f32x4 acc[2][2] = {};

#define STAGE(buf, kt_) do {                                                  \
    _Pragma("unroll")                                                         \
    for (int i = 0; i < 2; ++i) {                                             \
      gload_lds16(aSrc[i] + (kt_) * 128, (char*)&As[buf][0][0] + ldsOff[i]);  \
      gload_lds16(bSrc[i] + (kt_) * 128, (char*)&Bs[buf][0][0] + ldsOff[i]);  \
    }                                                                         \
  } while (0)

  STAGE(0, 0);

  for (int kt = 0; kt < 16; ++kt) {
    const int cur = kt & 1;
    if (kt < 15) {
      STAGE(cur ^ 1, kt + 1);
      asm volatile("s_waitcnt vmcnt(4)" ::: "memory");
    } else {
      asm volatile("s_waitcnt vmcnt(0)" ::: "memory");
    }
    asm volatile("s_barrier" ::: "memory");

    #pragma unroll
    for (int ks = 0; ks < 2; ++ks) {
      bf16x8 af[2], bf_[2];
      #pragma unroll
      for (int i = 0; i < 2; ++i) {
        const int row = wr * 32 + i * 16 + c;   // row&7 == c&7
        af[i] = *(const bf16x8*)((char*)&As[cur][0][0] + row * 128 +
                                 (((ks * 4 + g) ^ (c & 7)) << 4));
      }
      #pragma unroll
      for (int j = 0; j < 2; ++j) {
        const int row = wc * 32 + j * 16 + c;
        bf_[j] = *(const bf16x8*)((char*)&Bs[cur][0][0] + row * 128 +
                                  (((ks * 4 + g) ^ (c & 7)) << 4));
      }
      __builtin_amdgcn_s_setprio(1);
      #pragma unroll
      for (int i = 0; i < 2; ++i)
        #pragma unroll
        for (int j = 0; j < 2; ++j)
          acc[i][j] = __builtin_amdgcn_mfma_f32_16x16x32_bf16(af[i], bf_[j], acc[i][j], 0, 0, 0);
      __builtin_amdgcn_s_setprio(0);
    }

    if (kt < 15) asm volatile("s_barrier" ::: "memory");
  }
#undef STAGE

  #pragma unroll
  for (int j = 0; j < 2; ++j) {
    const int col = n0 + wc * 32 + j * 16 + c;
    const float bv = bo[col];
    #pragma unroll
    for (int i = 0; i < 2; ++i) {
      const int rowb = m0 + wr * 32 + i * 16 + 4 * g;
      #pragma unroll
      for (int r = 0; r < 4; ++r)
        C[(size_t)(rowb + r) * 1024 + col] = acc[i][j][r] + bv;
    }
  }
}

extern "C" void kernel_launch(void* const* d_in, const int* in_sizes, int n_in,
                              void* d_out, int out_size, void* d_ws, size_t ws_size,
                              hipStream_t stream) {
  const float* values = (const float*)d_in[0];
  const float* query  = (const float*)d_in[1];
  const float* key    = (const float*)d_in[2];
  const int*   mask   = (const int*)d_in[3];
  const float* Wv     = (const float*)d_in[4];
  const float* Wk     = (const float*)d_in[5];
  const float* Wq     = (const float*)d_in[6];
  const float* Wo     = (const float*)d_in[7];
  const float* bo     = (const float*)d_in[8];
  float* out = (float*)d_out;

  char* ws = (char*)d_ws;
  unsigned short* qb = (unsigned short*)(ws);                            // 8MB  [N][H][S][Dpi]
  unsigned short* kb = (unsigned short*)(ws + (size_t)8 * 1024 * 1024);  // 8MB  [N][H][S][Dpi]
  unsigned short* vb = (unsigned short*)(ws + (size_t)16 * 1024 * 1024); // 8MB  V^T [N][H][D][S]
  unsigned short* ob = (unsigned short*)(ws + (size_t)24 * 1024 * 1024); // 8MB  [N][S][Epi]
  unsigned long long* mb = (unsigned long long*)(ws + (size_t)32 * 1024 * 1024);   // 512KB
  unsigned short* wob = (unsigned short*)(ws + (size_t)33 * 1024 * 1024);          // 2MB

  k_pp<<<8192, 256, 0, stream>>>(mask, Wo, Wv, Wq, Wk, values, query, key, mb, wob, vb, qb, kb);
  k_attn<<<1024, 256, 0, stream>>>(qb, kb, vb, mb, ob);
  k_gemm<<<1024, 256, 0, stream>>>(ob, wob, bo, out);
}